// Round 16
// baseline (128.986 us; speedup 1.0000x reference)
//
#include <hip/hip_runtime.h>

#define NUM_NODES 100000
#define INPUT_DIM 256
#define NUM_BAGS  2048
#define BAG_SIZE  64
#define N_EDGES   3200000
#define NQUAD     (N_EDGES / 4)   // 800000
#define P_PART    8
#define NPP       12500           // 50 KB static LDS
#define NSLICE    32
#define QPS       (NQUAD / NSLICE)   // 25000

typedef unsigned int u32;
typedef float f4 __attribute__((ext_vector_type(4)));

// Pass A: pack (src, w) into one u32 per edge.
//   word = (src << 15) | bf15(nw[nbr])
__global__ void __launch_bounds__(256)
pack_edges(const int* __restrict__ edge_src, const int* __restrict__ edge_nbr,
           const float* __restrict__ nw, u32* __restrict__ packed) {
    const int q = blockIdx.x * 256 + threadIdx.x;
    const int4 s4 = ((const int4*)edge_src)[q];
    const int4 n4 = ((const int4*)edge_nbr)[q];
#define PACK(S, N)  (((u32)(S) << 15) |                                     \
                     (((__float_as_uint(nw[(N)]) + 0x8000u) >> 16) & 0x7FFFu))
    uint4 o;
    o.x = PACK(s4.x, n4.x);
    o.y = PACK(s4.y, n4.y);
    o.z = PACK(s4.z, n4.z);
    o.w = PACK(s4.w, n4.w);
#undef PACK
    ((uint4*)packed)[q] = o;
}

// Pass B: R13's P=8 partitioned LDS histogram (ABLATION: launched 4x this
// round; idempotent, so extra runs only cost time -> delta = 3 * T_hist).
__global__ void __launch_bounds__(1024)
hist_p(const u32* __restrict__ packed, float* __restrict__ rep) {
    __shared__ float hist[NPP];
    const int i    = blockIdx.x;
    const int r    = i & 7;
    const int p    = (i >> 3) & 7;
    const int b    = r | ((i >> 6) << 3);      // 0..31
    const int base = p * NPP;

    for (int j = threadIdx.x; j < NPP / 4; j += 1024)
        ((f4*)hist)[j] = (f4){0.f, 0.f, 0.f, 0.f};
    __syncthreads();

    const int lo = b * QPS;
#define EDGE(W)                                                          \
        {                                                                \
            const u32 rel = ((W) >> 15) - (u32)base;                     \
            if (rel < (u32)NPP)                                          \
                atomicAdd(&hist[rel],                                    \
                          __uint_as_float(((W) & 0x7FFFu) << 16));       \
        }
    for (int q = lo + (int)threadIdx.x; q < lo + QPS; q += 1024) {
        const uint4 a = ((const uint4*)packed)[q];
        EDGE(a.x) EDGE(a.y) EDGE(a.z) EDGE(a.w)
    }
#undef EDGE
    __syncthreads();

    float* dst = rep + (size_t)b * NUM_NODES + base;
    for (int j = threadIdx.x; j < NPP / 4; j += 1024) {
        const f4 v = ((const f4*)hist)[j];
        __builtin_nontemporal_store(v, &((f4*)dst)[j]);
    }
}

// Fused: blocks [0,RED_BLK) reduce rep -> nbr_sum; rest do dense GEMV.
#define RED_BLK 98
__global__ void __launch_bounds__(256)
gemv_reduce(const float* __restrict__ rep, float* __restrict__ nbr_sum,
            const float* __restrict__ x, const float* __restrict__ theta,
            float* __restrict__ h) {
    if (blockIdx.x < RED_BLK) {
        const int i = blockIdx.x * 256 + threadIdx.x;
        if (i >= NUM_NODES / 4) return;
        float4 a = make_float4(0.f, 0.f, 0.f, 0.f);
        #pragma unroll 8
        for (int r = 0; r < NSLICE; ++r) {
            const float4 v = ((const float4*)(rep + (size_t)r * NUM_NODES))[i];
            a.x += v.x; a.y += v.y; a.z += v.z; a.w += v.w;
        }
        float4 o;
        o.x = a.x > 0.f ? a.x : 1.0f;
        o.y = a.y > 0.f ? a.y : 1.0f;
        o.z = a.z > 0.f ? a.z : 1.0f;
        o.w = a.w > 0.f ? a.w : 1.0f;
        ((float4*)nbr_sum)[i] = o;
    } else {
        const int gb   = blockIdx.x - RED_BLK;
        const int lane = threadIdx.x & 63;
        const int wave = threadIdx.x >> 6;
        const float4 tw = *reinterpret_cast<const float4*>(&theta[lane * 4]);
        for (int row = gb * 4 + wave; row < NUM_NODES; row += 2048 * 4) {
            const float4 xv =
                *reinterpret_cast<const float4*>(&x[(size_t)row * INPUT_DIM + lane * 4]);
            float d = xv.x * tw.x + xv.y * tw.y + xv.z * tw.z + xv.w * tw.w;
            #pragma unroll
            for (int off = 32; off >= 1; off >>= 1)
                d += __shfl_xor(d, off);
            if (lane == 0) h[row] = d;
        }
    }
}

// Final: out[bag] = sum_item h[idx] * nbr_sum[idx] * alpha
__global__ void __launch_bounds__(256)
bag_final(const int* __restrict__ bags, const float* __restrict__ alpha,
          const float* __restrict__ h, const float* __restrict__ ns,
          float* __restrict__ out) {
    const int bag  = blockIdx.x * 4 + (threadIdx.x >> 6);
    const int lane = threadIdx.x & 63;
    const int idx  = bags[bag * BAG_SIZE + lane];
    float v = h[idx] * ns[idx] * alpha[bag * BAG_SIZE + lane];
    #pragma unroll
    for (int off = 32; off >= 1; off >>= 1)
        v += __shfl_xor(v, off);
    if (lane == 0) out[bag] = v;
}

// Tiny-ws fallback.
__global__ void __launch_bounds__(256)
edge_atomic(const int* __restrict__ edge_src, const int* __restrict__ edge_nbr,
            const float* __restrict__ nw, float* __restrict__ nbr_sum) {
    const int t = blockIdx.x * blockDim.x + threadIdx.x;
    const int4 s4 = ((const int4*)edge_src)[t];
    const int4 n4 = ((const int4*)edge_nbr)[t];
    atomicAdd(&nbr_sum[s4.x], nw[n4.x]);
    atomicAdd(&nbr_sum[s4.y], nw[n4.y]);
    atomicAdd(&nbr_sum[s4.z], nw[n4.z]);
    atomicAdd(&nbr_sum[s4.w], nw[n4.w]);
}

__global__ void __launch_bounds__(256)
fixup_nosum(float* __restrict__ nbr_sum) {
    const int i = blockIdx.x * 256 + threadIdx.x;
    if (i < NUM_NODES && nbr_sum[i] == 0.f) nbr_sum[i] = 1.0f;
}

__global__ void __launch_bounds__(256)
gemv_h(const float* __restrict__ x, const float* __restrict__ theta,
       float* __restrict__ h) {
    const int lane = threadIdx.x & 63;
    const int wave = threadIdx.x >> 6;
    const float4 tw = *reinterpret_cast<const float4*>(&theta[lane * 4]);
    const int stride = gridDim.x * 4;
    for (int row = blockIdx.x * 4 + wave; row < NUM_NODES; row += stride) {
        const float4 xv =
            *reinterpret_cast<const float4*>(&x[(size_t)row * INPUT_DIM + lane * 4]);
        float d = xv.x * tw.x + xv.y * tw.y + xv.z * tw.z + xv.w * tw.w;
        #pragma unroll
        for (int off = 32; off >= 1; off >>= 1)
            d += __shfl_xor(d, off);
        if (lane == 0) h[row] = d;
    }
}

extern "C" void kernel_launch(void* const* d_in, const int* in_sizes, int n_in,
                              void* d_out, int out_size, void* d_ws, size_t ws_size,
                              hipStream_t stream) {
    const float* x            = (const float*)d_in[0];
    const int*   bags         = (const int*)d_in[1];
    const float* alpha        = (const float*)d_in[2];
    const int*   edge_src     = (const int*)d_in[3];
    const int*   edge_nbr     = (const int*)d_in[4];
    const float* node_weights = (const float*)d_in[5];
    const float* theta        = (const float*)d_in[6];
    float*       out          = (float*)d_out;

    const size_t need_full =
        ((size_t)N_EDGES + (size_t)NSLICE * NUM_NODES + 2 * (size_t)NUM_NODES) * 4;

    if (ws_size >= need_full) {
        u32*   packed  = (u32*)d_ws;
        float* rep     = (float*)d_ws + N_EDGES;
        float* nbr_sum = rep + (size_t)NSLICE * NUM_NODES;
        float* h       = nbr_sum + NUM_NODES;

        pack_edges<<<NQUAD / 256, 256, 0, stream>>>(edge_src, edge_nbr,
                                                    node_weights, packed);
        // ABLATION: 4 identical runs; delta over R13 = 3 * T_hist.
        hist_p<<<P_PART * NSLICE, 1024, 0, stream>>>(packed, rep);
        hist_p<<<P_PART * NSLICE, 1024, 0, stream>>>(packed, rep);
        hist_p<<<P_PART * NSLICE, 1024, 0, stream>>>(packed, rep);
        hist_p<<<P_PART * NSLICE, 1024, 0, stream>>>(packed, rep);
        gemv_reduce<<<RED_BLK + 2048, 256, 0, stream>>>(rep, nbr_sum, x, theta, h);
        bag_final<<<NUM_BAGS / 4, 256, 0, stream>>>(bags, alpha, h, nbr_sum, out);
    } else {
        float* nbr_sum = (float*)d_ws;
        float* h       = nbr_sum + NUM_NODES;
        hipMemsetAsync(nbr_sum, 0, (size_t)NUM_NODES * 4, stream);
        edge_atomic<<<(N_EDGES / 4) / 256, 256, 0, stream>>>(
            edge_src, edge_nbr, node_weights, nbr_sum);
        fixup_nosum<<<(NUM_NODES + 255) / 256, 256, 0, stream>>>(nbr_sum);
        gemv_h<<<2048, 256, 0, stream>>>(x, theta, h);
        bag_final<<<NUM_BAGS / 4, 256, 0, stream>>>(bags, alpha, h, nbr_sum, out);
    }
}